// Round 14
// baseline (206.935 us; speedup 1.0000x reference)
//
#include <hip/hip_runtime.h>

typedef float  f4    __attribute__((ext_vector_type(4)));
typedef float  f32x4 __attribute__((ext_vector_type(4)));
typedef short  s16x8 __attribute__((ext_vector_type(8)));
typedef unsigned int u32x4 __attribute__((ext_vector_type(4)));

#define L_SEQ 2048
#define D4    16
#define NC4   512
#define RAD   128
#define NBH   48

// Split architecture (R11-proven): Z streams the zero complement first, then
// B computes the band windows. Coverage contract (HW-validated since R10):
// for each 16-aligned row-tile ibt, window = [max(0,ibt-128), min(2048,ibt+144));
// B writes it band-masked, Z writes the exact chunk complement.
// R14 change (single diff vs R11): B tile 64 -> 128 rows (512 thr, 8 waves,
// KROWS 384, LDS 48KB -> 3 blocks/CU) -- halves block/barrier count and K
// re-read. B internals otherwise R11 verbatim (A=Q, B=K, scalar stores).

__device__ __forceinline__ unsigned bf16rne(float f) {
    unsigned u = __float_as_uint(f);
    return (u + 0x7FFFu + ((u >> 16) & 1u)) >> 16;   // round-to-nearest-even
}

// ---------------- Kernel Z: pure streaming zero-fill of the complement ----------------
#define ZROWS 16
#define ZBLK  (NBH * (L_SEQ / ZROWS))   // 6144

__global__ __launch_bounds__(256)
void zero_oob(float* __restrict__ outg)
{
    const int t  = threadIdx.x;
    const int id = blockIdx.x;
    const int bh = id >> 7;
    const int r0 = (id & 127) * ZROWS;          // 16-aligned row-tile base
    f4* __restrict__ O4 = reinterpret_cast<f4*>(outg) + (size_t)bh * L_SEQ * NC4;

    const int wlo = (r0 > RAD ? r0 - RAD : 0) >> 2;
    const int whe = r0 + 144;
    const int whi = (whe < L_SEQ ? whe : L_SEQ) >> 2;
    const int wid = whi - wlo;                  // 36..68
    const int nz  = NC4 - wid;                  // 444..476 zero chunks per row

    const int  jA  = t < wlo ? t : t + wid;     // t < nz always
    const int  z2  = t + 256;
    const int  jB  = z2 < wlo ? z2 : z2 + wid;
    const bool doB = z2 < nz;
    const f4 zero4 = {0.f, 0.f, 0.f, 0.f};

#pragma unroll
    for (int r = 0; r < ZROWS; ++r) {
        f4* rowp = O4 + (size_t)(r0 + r) * NC4;
        rowp[jA] = zero4;
        if (doB) rowp[jB] = zero4;
    }
}

// ---------------- Kernel B: MFMA band compute (R11 internals, TI=128) ----------------
#define TI    128            // rows per block (8 waves x 16-row MFMA tiles)
#define NTIL  (L_SEQ / TI)   // 16
#define BBLK  (NBH * NTIL)   // 768
#define KROWS (TI + 2*RAD)   // 384 staged K rows

__global__ __launch_bounds__(512, 6)
void band_mfma(const float* __restrict__ Qg, const float* __restrict__ Kg,
               float* __restrict__ outg)
{
    // K rows as 8 16B-units (8 bf16, d-ascending); slot = si*8 + (u ^ (si&7))
    // -> staging writes and 16-lane A/B-frag reads both conflict-free.
    __shared__ u32x4 sK[KROWS * 8];     // 49152 B -> 3 blocks/CU

    const int t  = threadIdx.x;
    const int id = blockIdx.x;
    // bijective XCD swizzle (BBLK % 8 == 0)
    const int swz = (id & 7) * (BBLK / 8) + (id >> 3);
    const int bh  = swz >> 4;
    const int i0  = (swz & (NTIL - 1)) * TI;

    const f4* __restrict__ K4 = reinterpret_cast<const f4*>(Kg) + (size_t)bh * L_SEQ * D4;
    const f4* __restrict__ Q4 = reinterpret_cast<const f4*>(Qg) + (size_t)bh * L_SEQ * D4;
    float* __restrict__ ob    = outg + (size_t)bh * L_SEQ * L_SEQ;

    const int kbase = i0 - RAD;

    // ---- stage K as bf16: 3072 units, 6 per thread (12 f4 global loads)
#pragma unroll 2
    for (int itr = 0; itr < 6; ++itr) {
        const int s  = itr * 512 + t;
        const int si = s >> 3, u = s & 7;
        int row = kbase + si;
        row = row < 0 ? 0 : (row > L_SEQ - 1 ? L_SEQ - 1 : row);  // clamp; never read (c-range guards)
        const f4 a = K4[(size_t)row * D4 + 2 * u];
        const f4 b = K4[(size_t)row * D4 + 2 * u + 1];
        u32x4 w;
        w.x = bf16rne(a.x) | (bf16rne(a.y) << 16);
        w.y = bf16rne(a.z) | (bf16rne(a.w) << 16);
        w.z = bf16rne(b.x) | (bf16rne(b.y) << 16);
        w.w = bf16rne(b.z) | (bf16rne(b.w) << 16);
        sK[si * 8 + (u ^ (si & 7))] = w;
    }

    // ---- MFMA band compute: wave wv owns 16-row tile ib = i0 + 16*wv
    const int wv = t >> 6, l = t & 63;
    const int ib = i0 + 16 * wv;
    const int m  = l & 15, g = l >> 4;

    // A-fragments straight from global Q (fp32 -> bf16), d = 8g.. / 32+8g..
    // (loaded after staging issue, before barrier -- latency hides under drain)
    s16x8 A1, A2;
    {
        const size_t qb = (size_t)(ib + m) * D4;
        const f4 qa = Q4[qb + 2 * g];
        const f4 qv = Q4[qb + 2 * g + 1];
        const f4 qc = Q4[qb + 8 + 2 * g];
        const f4 qd = Q4[qb + 8 + 2 * g + 1];
        u32x4 wa, wb;
        wa.x = bf16rne(qa.x) | (bf16rne(qa.y) << 16);
        wa.y = bf16rne(qa.z) | (bf16rne(qa.w) << 16);
        wa.z = bf16rne(qv.x) | (bf16rne(qv.y) << 16);
        wa.w = bf16rne(qv.z) | (bf16rne(qv.w) << 16);
        wb.x = bf16rne(qc.x) | (bf16rne(qc.y) << 16);
        wb.y = bf16rne(qc.z) | (bf16rne(qc.w) << 16);
        wb.z = bf16rne(qd.x) | (bf16rne(qd.y) << 16);
        wb.w = bf16rne(qd.z) | (bf16rne(qd.w) << 16);
        A1 = __builtin_bit_cast(s16x8, wa);
        A2 = __builtin_bit_cast(s16x8, wb);
    }
    __syncthreads();

    {
        const int c_lo  = (ib < RAD) ? ((RAD - ib) >> 4) : 0;       // skip j<0 tiles
        const int c_hi0 = (2176 - ib) >> 4;                         // skip j>=2048 tiles
        const int c_hi  = c_hi0 < 17 ? c_hi0 : 17;
        for (int c = c_lo; c < c_hi; ++c) {
            const int si = 16 * (wv + c) + m;                       // staged K row for col j
            const u32x4 b1 = sK[si * 8 + ((g    ) ^ (si & 7))];
            const u32x4 b2 = sK[si * 8 + ((4 + g) ^ (si & 7))];
            f32x4 acc = {0.f, 0.f, 0.f, 0.f};
            acc = __builtin_amdgcn_mfma_f32_16x16x32_bf16(A1, __builtin_bit_cast(s16x8, b1), acc, 0, 0, 0);
            acc = __builtin_amdgcn_mfma_f32_16x16x32_bf16(A2, __builtin_bit_cast(s16x8, b2), acc, 0, 0, 0);
            const int j = ib - RAD + 16 * c + m;                    // C col = lane&15
#pragma unroll
            for (int r = 0; r < 4; ++r) {
                const int i = ib + 4 * g + r;                       // C row = 4*(lane>>4)+reg
                const float v = ((unsigned)(i - j + RAD) <= 2u * RAD) ? acc[r] : 0.f;
                ob[(size_t)i * L_SEQ + j] = v;
            }
        }
    }
}

extern "C" void kernel_launch(void* const* d_in, const int* in_sizes, int n_in,
                              void* d_out, int out_size, void* d_ws, size_t ws_size,
                              hipStream_t stream) {
    const float* Q = (const float*)d_in[0];
    const float* K = (const float*)d_in[1];
    float* out = (float*)d_out;
    zero_oob<<<ZBLK, 256, 0, stream>>>(out);
    band_mfma<<<BBLK, 512, 0, stream>>>(Q, K, out);
}

// Round 15
// 160.254 us; speedup vs baseline: 1.2913x; 1.2913x over previous
//
#include <hip/hip_runtime.h>

typedef float  f4    __attribute__((ext_vector_type(4)));
typedef float  f32x4 __attribute__((ext_vector_type(4)));
typedef short  s16x8 __attribute__((ext_vector_type(8)));
typedef unsigned int u32x4 __attribute__((ext_vector_type(4)));

#define L_SEQ 2048
#define D4    16
#define NC4   512
#define RAD   128
#define NBH   48
#define TI    32
#define NTIL  (L_SEQ / TI)     // 64
#define NBLK  (NBH * NTIL)     // 3072
#define KROWS 288              // staged K rows = window cols [i0-128, i0+160)
#define HSTR  296              // band-buffer row stride in ushort (74 uint2)

// Compute-then-sweep single kernel. Block = 256 thr (4 waves), 32 rows.
//  Phase 1: stage K window as bf16 in LDS (R10-proven swizzled layout).
//  Phase 2: MFMA the 2 row-tiles x 18 col-tiles; band-masked results go to
//           an LDS band buffer as bf16 (NO global stores in this phase).
//  Phase 3: every wave writes 8 COMPLETE rows linearly (1KB/wave-inst,
//           8KB sequential per row), merging zeros with band values from
//           LDS. All 805 MB of output is fill-kernel-shaped traffic; zero
//           scalar stores.
// Coverage: sweep writes every chunk of every row exactly once; band window
// [max(0,i04-32), min(512,i04+40)) comes from LDS (values band-masked at
// C-write, so spare window cols are zeros), the rest is zero.

__device__ __forceinline__ unsigned bf16rne(float f) {
    unsigned u = __float_as_uint(f);
    return (u + 0x7FFFu + ((u >> 16) & 1u)) >> 16;   // round-to-nearest-even
}

__global__ __launch_bounds__(256, 2)
void band_sweep(const float* __restrict__ Qg, const float* __restrict__ Kg,
                float* __restrict__ outg)
{
    // K rows as 8 16B-units (8 bf16, d-ascending); slot = si*8 + (u ^ (si&7))
    __shared__ u32x4 sK[KROWS * 8];            // 36864 B
    __shared__ unsigned short sH[TI * HSTR];   // 18944 B (total 55808 -> 2 blocks/CU)

    const int t  = threadIdx.x;
    const int id = blockIdx.x;
    // bijective XCD swizzle (NBLK % 8 == 0)
    const int swz = (id & 7) * (NBLK / 8) + (id >> 3);
    const int bh  = swz >> 6;
    const int i0  = (swz & (NTIL - 1)) * TI;
    const int i04 = i0 >> 2;

    const f4* __restrict__ K4 = reinterpret_cast<const f4*>(Kg) + (size_t)bh * L_SEQ * D4;
    const f4* __restrict__ Q4 = reinterpret_cast<const f4*>(Qg) + (size_t)bh * L_SEQ * D4;
    f4* __restrict__ O4       = reinterpret_cast<f4*>(outg)     + (size_t)bh * L_SEQ * NC4;

    const int kbase = i0 - RAD;

    // ---- phase 1: stage K rows [i0-128, i0+160) as bf16: 2304 units, 9/thread
#pragma unroll 3
    for (int itr = 0; itr < 9; ++itr) {
        const int s  = itr * 256 + t;
        const int si = s >> 3, u = s & 7;
        int row = kbase + si;
        row = row < 0 ? 0 : (row > L_SEQ - 1 ? L_SEQ - 1 : row);  // clamp; masked at C-write
        const f4 a = K4[(size_t)row * D4 + 2 * u];
        const f4 b = K4[(size_t)row * D4 + 2 * u + 1];
        u32x4 w;
        w.x = bf16rne(a.x) | (bf16rne(a.y) << 16);
        w.y = bf16rne(a.z) | (bf16rne(a.w) << 16);
        w.z = bf16rne(b.x) | (bf16rne(b.y) << 16);
        w.w = bf16rne(b.z) | (bf16rne(b.w) << 16);
        sK[si * 8 + (u ^ (si & 7))] = w;
    }

    const int wv = t >> 6, l = t & 63, m = l & 15, g = l >> 4;
    const int rt = wv & 1;              // row-tile (0/1); waves 0,1: even c; 2,3: odd c
    const int ib = i0 + 16 * rt;

    // Q A-frags (issued after staging loads; latency hides under the drain)
    s16x8 A1, A2;
    {
        const size_t qb = (size_t)(ib + m) * D4;
        const f4 qa = Q4[qb + 2 * g];
        const f4 qv = Q4[qb + 2 * g + 1];
        const f4 qc = Q4[qb + 8 + 2 * g];
        const f4 qd = Q4[qb + 8 + 2 * g + 1];
        u32x4 wa, wb;
        wa.x = bf16rne(qa.x) | (bf16rne(qa.y) << 16);
        wa.y = bf16rne(qa.z) | (bf16rne(qa.w) << 16);
        wa.z = bf16rne(qv.x) | (bf16rne(qv.y) << 16);
        wa.w = bf16rne(qv.z) | (bf16rne(qv.w) << 16);
        wb.x = bf16rne(qc.x) | (bf16rne(qc.y) << 16);
        wb.y = bf16rne(qc.z) | (bf16rne(qc.w) << 16);
        wb.z = bf16rne(qd.x) | (bf16rne(qd.y) << 16);
        wb.w = bf16rne(qd.z) | (bf16rne(qd.w) << 16);
        A1 = __builtin_bit_cast(s16x8, wa);
        A2 = __builtin_bit_cast(s16x8, wb);
    }
    __syncthreads();

    // ---- phase 2: MFMA -> band-masked bf16 values into sH
    {
        const int ilb = 16 * rt + 4 * g;
#pragma unroll 1
        for (int k = 0; k < 9; ++k) {
            const int c  = (wv >> 1) + 2 * k;           // col-tile 0..17
            const int si = 16 * c + m;
            const u32x4 b1 = sK[si * 8 + ((g    ) ^ (si & 7))];
            const u32x4 b2 = sK[si * 8 + ((4 + g) ^ (si & 7))];
            f32x4 acc = {0.f, 0.f, 0.f, 0.f};
            acc = __builtin_amdgcn_mfma_f32_16x16x32_bf16(A1, __builtin_bit_cast(s16x8, b1), acc, 0, 0, 0);
            acc = __builtin_amdgcn_mfma_f32_16x16x32_bf16(A2, __builtin_bit_cast(s16x8, b2), acc, 0, 0, 0);
            const int j = kbase + si;                   // global col (C col = lane&15)
#pragma unroll
            for (int r = 0; r < 4; ++r) {
                const int i = i0 + ilb + r;             // C row = 4*(lane>>4)+reg
                const float v = ((unsigned)(i - j + RAD) <= 2u * RAD) ? acc[r] : 0.f;
                sH[(ilb + r) * HSTR + si] = (unsigned short)bf16rne(v);
            }
        }
    }
    __syncthreads();

    // ---- phase 3: linear full-row sweep (zeros + band), 1KB per wave-inst
    {
        const uint2* sU2 = reinterpret_cast<const uint2*>(sH);
        const int clo  = i04 - 32 < 0 ? 0 : i04 - 32;   // window chunk range
        const int chi  = i04 + 40 > NC4 ? NC4 : i04 + 40;
        const int base = i04 - 32;                      // chunk -> band-col offset
#pragma unroll 1
        for (int rr = 0; rr < 8; ++rr) {
            const int il = wv * 8 + rr;                 // local row 0..31
            f4* rowp = O4 + (size_t)(i0 + il) * NC4;
            const int ub = il * (HSTR / 4);             // uint2 row base = il*74
#pragma unroll
            for (int kk = 0; kk < 8; ++kk) {
                const int ch = kk * 64 + l;             // chunk 0..511, coalesced
                int off = ch - base;
                off = off < 0 ? 0 : (off > 71 ? 71 : off);   // clamp; selected below
                const uint2 w = sU2[ub + off];
                f4 v;
                v.x = __uint_as_float(w.x << 16);
                v.y = __uint_as_float(w.x & 0xffff0000u);
                v.z = __uint_as_float(w.y << 16);
                v.w = __uint_as_float(w.y & 0xffff0000u);
                if (!((ch >= clo) & (ch < chi))) v = f4{0.f, 0.f, 0.f, 0.f};
                rowp[ch] = v;
            }
        }
    }
}

extern "C" void kernel_launch(void* const* d_in, const int* in_sizes, int n_in,
                              void* d_out, int out_size, void* d_ws, size_t ws_size,
                              hipStream_t stream) {
    const float* Q = (const float*)d_in[0];
    const float* K = (const float*)d_in[1];
    float* out = (float*)d_out;
    band_sweep<<<NBLK, 256, 0, stream>>>(Q, K, out);
}